// Round 1
// baseline (31.681 us; speedup 1.0000x reference)
//
#include <hip/hip_runtime.h>
#include <math.h>

// Gather data_input[r,c] * w and atomically accumulate into A_raw[r].
__global__ void na_gather_kernel(const float* __restrict__ data,
                                 const int* __restrict__ rows,
                                 const int* __restrict__ cols,
                                 const float* __restrict__ vals,
                                 float* __restrict__ A_raw,
                                 int E, int N) {
    int e = blockIdx.x * blockDim.x + threadIdx.x;
    if (e < E) {
        int r = rows[e];
        int c = cols[e];
        float v = data[(size_t)r * (size_t)N + (size_t)c] * vals[e];
        atomicAdd(&A_raw[r], v);
    }
}

// Single-block softmax over N elements (N <= 16384). alpha = softmax(A_raw).
__global__ __launch_bounds__(1024)
void na_softmax_kernel(const float* __restrict__ A_raw,
                       float* __restrict__ alpha,
                       int N) {
    const int t = threadIdx.x;
    const int VPT = (N + 1023) / 1024;   // values per thread (8 for N=8192)

    float x[16];
    float m = -INFINITY;
    for (int i = 0; i < VPT; ++i) {
        int idx = t + i * 1024;
        x[i] = (idx < N) ? A_raw[idx] : -INFINITY;
        m = fmaxf(m, x[i]);
    }

    // wave (64-lane) max reduce
    #pragma unroll
    for (int off = 1; off < 64; off <<= 1)
        m = fmaxf(m, __shfl_xor(m, off, 64));

    __shared__ float smax[16];
    __shared__ float ssum[16];
    const int wave = t >> 6;           // 16 waves
    if ((t & 63) == 0) smax[wave] = m;
    __syncthreads();

    float bm = smax[0];
    #pragma unroll
    for (int i = 1; i < 16; ++i) bm = fmaxf(bm, smax[i]);

    // sum of exp
    float s = 0.0f;
    float ex[16];
    for (int i = 0; i < VPT; ++i) {
        int idx = t + i * 1024;
        ex[i] = (idx < N) ? expf(x[i] - bm) : 0.0f;
        s += ex[i];
    }
    #pragma unroll
    for (int off = 1; off < 64; off <<= 1)
        s += __shfl_xor(s, off, 64);
    if ((t & 63) == 0) ssum[wave] = s;
    __syncthreads();

    float total = 0.0f;
    #pragma unroll
    for (int i = 0; i < 16; ++i) total += ssum[i];
    const float inv = 1.0f / total;

    for (int i = 0; i < VPT; ++i) {
        int idx = t + i * 1024;
        if (idx < N) alpha[idx] = ex[i] * inv;
    }
}

extern "C" void kernel_launch(void* const* d_in, const int* in_sizes, int n_in,
                              void* d_out, int out_size, void* d_ws, size_t ws_size,
                              hipStream_t stream) {
    const float* data = (const float*)d_in[0];
    const int*   rows = (const int*)d_in[1];
    const int*   cols = (const int*)d_in[2];
    const float* vals = (const float*)d_in[3];

    const int N = out_size / 2;          // 8192
    const int E = in_sizes[1];           // 262144

    float* alpha = (float*)d_out;        // first N floats
    float* A_raw = alpha + N;            // second N floats

    // Must zero the accumulator every call (harness poisons once, no re-poison).
    hipMemsetAsync(A_raw, 0, (size_t)N * sizeof(float), stream);

    const int threads = 256;
    const int blocks = (E + threads - 1) / threads;
    na_gather_kernel<<<blocks, threads, 0, stream>>>(data, rows, cols, vals, A_raw, E, N);

    na_softmax_kernel<<<1, 1024, 0, stream>>>(A_raw, alpha, N);
}